// Round 6
// baseline (459.598 us; speedup 1.0000x reference)
//
#include <hip/hip_runtime.h>

#define Tdim 1024
#define Ndim 64
#define FSZ (8 * 1024 * 64 * 8)

typedef unsigned uint2v __attribute__((ext_vector_type(2)));

// v + dpp(v) at VALU latency. ctrl: 0xB1=quad_perm[1,0,3,2](xor1),
// 0x4E=quad_perm[2,3,0,1](xor2), 0x141=row_half_mirror(xor7),
// 0x128=row_ror:8(xor8).
#define DPPADD(v, ctrl) ((v) + __int_as_float(__builtin_amdgcn_update_dpp( \
    0, __float_as_int(v), ctrl, 0xF, 0xF, false)))

__device__ __forceinline__ float swap_add16(float v) {  // + value from lane^16
  unsigned u = __float_as_uint(v);
  uint2v r = __builtin_amdgcn_permlane16_swap(u, u, false, false);
  return __uint_as_float(r[0]) + __uint_as_float(r[1]);
}
__device__ __forceinline__ float swap_add32(float v) {  // + value from lane^32
  unsigned u = __float_as_uint(v);
  uint2v r = __builtin_amdgcn_permlane32_swap(u, u, false, false);
  return __uint_as_float(r[0]) + __uint_as_float(r[1]);
}

// sum over lane bits {0,1,2}: xor1, xor2, then xor7 (== xor4 after bits 0,1 summed)
#define SUM_LO3(v) { v = DPPADD(v, 0xB1); v = DPPADD(v, 0x4E); v = DPPADD(v, 0x141); }
// sum over lane bits {3,4,5}: xor8 (row_ror:8), xor16, xor32 (permlane swaps)
#define SUM_HI3(v) { v = DPPADD(v, 0x128); v = swap_add16(v); v = swap_add32(v); }

// Fire-and-forget global->LDS DMA: LDS dest = uniform base + lane*4,
// global source is per-lane (this is how the XOR swizzle is applied).
#define GLOAD_LDS(gp, lp) __builtin_amdgcn_global_load_lds( \
    (const __attribute__((address_space(1))) unsigned*)(gp), \
    (__attribute__((address_space(3))) unsigned*)(lp), 4, 0, 0)

// ---------------- kernel 1: forward + beta recursions ----------------
// One wave per chain (1/SIMD, zero TLP -> all stalls are exposed).
// Rounds 2-4 pathology: per-step LDS reads while DMA loads + exec-masked
// stores are outstanding -> conservative `s_waitcnt vmcnt(0)` inside the
// batch, repeatedly draining the prefetch (~400 stall cyc/step at constant
// VALUBusy 37%). This version is conservatism-proof: per 16-step batch
//   [one implicit vmcnt(0), residual ~0] -> 32-ds_read burst into regs
//   -> issue next batch's 18 gload_lds -> pure-VALU 16-step compute
//   (outputs go to sLa via ds_write: no vmcnt) -> packed 2-dword/lane store.
// A staged XOR-swizzled (src-side swizzle, linear LDS dest): identity read
// slot=swz(lane), transposed read slot=trw(lane); both 2 lanes/bank (free).

__device__ __forceinline__ void stage_fwd(const float* __restrict__ a_base,
                                          const float* __restrict__ b_base,
                                          int t0, int swz, int lane,
                                          float* sA, float* sB) {
#pragma unroll
  for (int s = 0; s < 16; ++s) {
    int t = t0 + s; if (t > Tdim - 1) t = Tdim - 1;
    GLOAD_LDS(&a_base[(size_t)t * (Ndim * 64) + swz], &sA[s * 64]);
  }
#pragma unroll
  for (int h = 0; h < 2; ++h) {
    int tb = t0 + h * 8 + (lane >> 3); if (tb > Tdim - 1) tb = Tdim - 1;
    GLOAD_LDS(&b_base[(size_t)tb * (Ndim * 8) + (lane & 7)], &sB[h * 64]);
  }
}

__device__ __forceinline__ void stage_bwd(const float* __restrict__ a_base,
                                          const float* __restrict__ b_base,
                                          int t0, int swz, int lane,
                                          float* sA, float* sB) {
#pragma unroll
  for (int s = 0; s < 16; ++s) {
    int t = t0 - s; if (t < 0) t = 0;
    GLOAD_LDS(&a_base[(size_t)t * (Ndim * 64) + swz], &sA[s * 64]);
  }
#pragma unroll
  for (int h = 0; h < 2; ++h) {
    int tb = t0 - 1 - (h * 8 + (lane >> 3)); if (tb < 0) tb = 0;  // b at tau-1
    GLOAD_LDS(&b_base[(size_t)tb * (Ndim * 8) + (lane & 7)], &sB[h * 64]);
  }
}

__global__ __launch_bounds__(64, 1) void chains_kernel(const float* __restrict__ A,
                                                       const float* __restrict__ Bm,
                                                       const float* __restrict__ Z1,
                                                       float* __restrict__ Fout,
                                                       float* __restrict__ Bout) {
  __shared__ float sA0[1024], sA1[1024], sB0[128], sB1[128], sLa[128];
  const int lane = threadIdx.x;
  const int x = lane >> 3, y = lane & 7;
  const int swz = (x << 3) | (y ^ x);   // involution: staging src == identity-read slot
  const int trw = (y << 3) | (x ^ y);   // transpose-read slot
  const int chain = blockIdx.x & 511;
  const int b = chain >> 6, n = chain & 63;
  const size_t cbase = ((size_t)b * Tdim) * Ndim + n;
  const float* a_base = A + cbase * 64;
  const float* b_base = Bm + cbase * 8;

  if (blockIdx.x < 512) {
    // ---- forward chain ----
    float* f_base = Fout + cbase * 8;
    float v0 = Z1[n * 8 + y] + b_base[y];
    float q = __expf(v0);                 // y(=j)-indexed, replicated across groups
    float T0 = q; SUM_LO3(T0);
    if (x == 0) f_base[y] = v0 - __logf(T0);
    float sc = __builtin_amdgcn_rcpf(T0);
    stage_fwd(a_base, b_base, 1, swz, lane, sA0, sB0);
#pragma unroll 1
    for (int kk = 0; kk < 64; ++kk) {
      const float* sA = (kk & 1) ? sA1 : sA0;
      const float* sB = (kk & 1) ? sB1 : sB0;
      float* nA = (kk & 1) ? sA0 : sA1;
      float* nB = (kk & 1) ? sB0 : sB1;
      const int t0 = 1 + kk * 16;
      float av[16], bv[16];                            // batch burst -> regs
#pragma unroll
      for (int s = 0; s < 16; ++s) {
        av[s] = sA[s * 64 + ((s & 1) ? trw : swz)];
        bv[s] = sB[s * 8 + ((s & 1) ? y : x)];
      }
      __builtin_amdgcn_sched_barrier(0);
      if (kk + 1 < 64) stage_fwd(a_base, b_base, t0 + 16, swz, lane, nA, nB);
      __builtin_amdgcn_sched_barrier(0);
#pragma unroll
      for (int s = 0; s < 16; ++s) {                   // pure-VALU core
        int oidx = (s & 1) ? y : x;                    // output state index role
        float v = __expf(av[s]) * q;                   // CHAIN
        if (!(s & 1)) { SUM_LO3(v); } else { SUM_HI3(v); }  // CHAIN: sum over j
        float S = v * (__expf(bv[s]) * sc);            // CHAIN (eb*sc off-chain)
        q = S;
        float T = S;                                   // norm path (parallel)
        if (!(s & 1)) { SUM_HI3(T); } else { SUM_LO3(T); }
        sc = __builtin_amdgcn_rcpf(T);                 // approx ok: scale cancels
        float la = __logf(S * sc);                     // log(S/T)
        if ((((s & 1) ? x : y)) == 0) sLa[s * 8 + oidx] = la;  // ds_write, no vmcnt
      }
      __builtin_amdgcn_sched_barrier(0);
#pragma unroll
      for (int h = 0; h < 2; ++h) {                    // packed store: 2 dwords/lane
        int t = t0 + x + h * 8;
        if (t < Tdim) f_base[(size_t)t * (Ndim * 8) + y] = sLa[h * 64 + lane];
      }
    }
  } else {
    // ---- backward (beta) chain ----
    float* bo = Bout + cbase * 8;
    float bT = b_base[(size_t)(Tdim - 1) * (Ndim * 8) + x];
    float u = __expf(bT);                 // x(=i)-indexed (beta_{T-1}=0)
    if (x == 0) bo[(size_t)(Tdim - 1) * (Ndim * 8) + y] = 0.f;
    float sc = 1.0f;
    stage_bwd(a_base, b_base, Tdim - 1, swz, lane, sA0, sB0);
#pragma unroll 1
    for (int kk = 0; kk < 64; ++kk) {
      const float* sA = (kk & 1) ? sA1 : sA0;
      const float* sB = (kk & 1) ? sB1 : sB0;
      float* nA = (kk & 1) ? sA0 : sA1;
      float* nB = (kk & 1) ? sB0 : sB1;
      const int t0 = Tdim - 1 - kk * 16;
      float av[16], bv[16];
#pragma unroll
      for (int s = 0; s < 16; ++s) {
        av[s] = sA[s * 64 + ((s & 1) ? trw : swz)];
        bv[s] = sB[s * 8 + ((s & 1) ? x : y)];
      }
      __builtin_amdgcn_sched_barrier(0);
      if (kk + 1 < 64) stage_bwd(a_base, b_base, t0 - 16, swz, lane, nA, nB);
      __builtin_amdgcn_sched_barrier(0);
#pragma unroll
      for (int s = 0; s < 16; ++s) {
        float v = __expf(av[s]) * u;                   // CHAIN
        if (!(s & 1)) { SUM_HI3(v); } else { SUM_LO3(v); }  // CHAIN: sum over i
        int oidx = (s & 1) ? x : y;                    // r's index role
        float unew = (__expf(bv[s]) * sc) * v;         // CHAIN tail
        float W = v;                                   // norm path (parallel)
        if (!(s & 1)) { SUM_LO3(W); } else { SUM_HI3(W); }
        float scn = __builtin_amdgcn_rcpf(W);
        float lb = __logf(v * scn);                    // log(v/W)
        if ((((s & 1) ? y : x)) == 0) sLa[s * 8 + oidx] = lb;
        u = unew;
        sc = scn;
      }
      __builtin_amdgcn_sched_barrier(0);
#pragma unroll
      for (int h = 0; h < 2; ++h) {
        int trow = t0 - (x + h * 8) - 1;
        if (trow >= 0) bo[(size_t)trow * (Ndim * 8) + y] = sLa[h * 64 + lane];
      }
    }
  }
}

// ---------------- kernel 2: gammas (memory-bound, float4 I/O) ----------------
// One lane per (b,t,n,i) row: 8 lanes per g, 8 g's per wave. A row and
// F_prev row loaded as float4x2 (16B/lane, coalesced 2KB/wave), j-sum fully
// in-register, i-sum via 3 DPP stages. g1: per-lane element, DPP group sum.
__global__ __launch_bounds__(256) void gamma_kernel(const float* __restrict__ A,
                                                    const float* __restrict__ Bm,
                                                    const float* __restrict__ F,
                                                    const float* __restrict__ Bo,
                                                    float* __restrict__ G1,
                                                    float* __restrict__ G2) {
  const int lane = threadIdx.x & 63;
  const int i = lane & 7;                               // row index within K
  const int gq = lane >> 3;                             // g within wave (0..7)
  const int g = (blockIdx.x * 4 + (threadIdx.x >> 6)) * 8 + gq;  // flat (b*T+t)*N+n
  const int t = (g >> 6) & (Tdim - 1);

  const float bo_i = Bo[(size_t)g * 8 + i];

  // gamma1: u1 = F+Bo, normalize over the 8-lane group
  {
    float u1 = F[(size_t)g * 8 + i] + bo_i;
    float s1 = __expf(u1);
    SUM_LO3(s1);
    G1[(size_t)g * 8 + i] = u1 - __logf(s1);
  }

  // gamma2
  float4* o = (float4*)&G2[(size_t)g * 64 + i * 8];
  if (t == 0) {
    float4 z = make_float4(0.f, 0.f, 0.f, 0.f);
    o[0] = z; o[1] = z;
  } else {
    const float4* ap = (const float4*)&A[(size_t)g * 64 + i * 8];
    float4 a0 = ap[0], a1 = ap[1];
    const float4* fp = (const float4*)&F[((size_t)g - Ndim) * 8];
    float4 f0 = fp[0], f1 = fp[1];
    float c = bo_i + Bm[(size_t)g * 8 + i];
    float v0 = c + a0.x + f0.x, v1 = c + a0.y + f0.y;
    float v2 = c + a0.z + f0.z, v3 = c + a0.w + f0.w;
    float v4 = c + a1.x + f1.x, v5 = c + a1.y + f1.y;
    float v6 = c + a1.z + f1.z, v7 = c + a1.w + f1.w;
    float r = ((__expf(v0) + __expf(v1)) + (__expf(v2) + __expf(v3)))
            + ((__expf(v4) + __expf(v5)) + (__expf(v6) + __expf(v7)));
    SUM_LO3(r);                                         // sum over i (8-lane group)
    float lq = __logf(r);
    o[0] = make_float4(v0 - lq, v1 - lq, v2 - lq, v3 - lq);
    o[1] = make_float4(v4 - lq, v5 - lq, v6 - lq, v7 - lq);
  }
}

extern "C" void kernel_launch(void* const* d_in, const int* in_sizes, int n_in,
                              void* d_out, int out_size, void* d_ws, size_t ws_size,
                              hipStream_t stream) {
  const float* A  = (const float*)d_in[0];   // (B,T,N,K,K)
  const float* Bm = (const float*)d_in[1];   // (B,T,N,K)
  const float* Z1 = (const float*)d_in[2];   // (N,K)
  float* out = (float*)d_out;
  float* Fout = out;                // forward_probs
  float* Bout = out + FSZ;          // backward_probs
  float* G1   = out + 2 * FSZ;      // gamma1
  float* G2   = out + 3 * FSZ;      // gamma2

  chains_kernel<<<dim3(1024), dim3(64), 0, stream>>>(A, Bm, Z1, Fout, Bout);
  gamma_kernel<<<dim3(8 * Tdim * Ndim / 32), dim3(256), 0, stream>>>(A, Bm, Fout, Bout, G1, G2);
}

// Round 7
// 458.939 us; speedup vs baseline: 1.0014x; 1.0014x over previous
//
#include <hip/hip_runtime.h>

#define Tdim 1024
#define Ndim 64
#define FSZ (8 * 1024 * 64 * 8)

typedef unsigned uint2v __attribute__((ext_vector_type(2)));

// v + dpp(v). ctrl: 0xB1=quad_perm[1,0,3,2](xor1), 0x4E=quad_perm[2,3,0,1](xor2),
// 0x141=row_half_mirror(xor7), 0x128=row_ror:8, 0x124=row_ror:4.
// Backend's GCNDPPCombine fuses mov_dpp+add -> v_add_f32_dpp.
#define DPPADD(v, ctrl) ((v) + __int_as_float(__builtin_amdgcn_update_dpp( \
    0, __float_as_int(v), ctrl, 0xF, 0xF, false)))

__device__ __forceinline__ float swap_add16(float v) {  // + value from lane^16
  unsigned u = __float_as_uint(v);
  uint2v r = __builtin_amdgcn_permlane16_swap(u, u, false, false);
  return __uint_as_float(r[0]) + __uint_as_float(r[1]);
}
__device__ __forceinline__ float swap_add32(float v) {  // + value from lane^32
  unsigned u = __float_as_uint(v);
  uint2v r = __builtin_amdgcn_permlane32_swap(u, u, false, false);
  return __uint_as_float(r[0]) + __uint_as_float(r[1]);
}

// sum over lane bits {0,1,2}: xor1, xor2, then xor7 (== xor4 after bits 0,1 summed)
#define SUM_LO3(v) { v = DPPADD(v, 0xB1); v = DPPADD(v, 0x4E); v = DPPADD(v, 0x141); }
// sum over lane bits {3,4,5}: xor8 (row_ror:8), xor16, xor32 (permlane swaps)
#define SUM_HI3(v) { v = DPPADD(v, 0x128); v = swap_add16(v); v = swap_add32(v); }

// Fire-and-forget global->LDS DMA (LDS dest = uniform base + lane*4; the XOR
// swizzle is applied on the per-lane GLOBAL source).
#define GLOAD_LDS(gp, lp) __builtin_amdgcn_global_load_lds( \
    (const __attribute__((address_space(1))) unsigned*)(gp), \
    (__attribute__((address_space(3))) unsigned*)(lp), 4, 0, 0)

// ---------------- kernel 1: forward + beta recursions ----------------
// One wave per chain (1/SIMD, zero TLP -> every dependent latency exposed).
// Round-6 falsified the waitcnt theory (1 drain/16 steps, still ~500cyc/step).
// Remaining critical path is the recurrence itself; this version removes the
// norm path (T-sum -> rcp -> mul) from the chain: per-step chain is now
// mul -> 3 DPP-adds -> mul. T/rcp/log run off-chain (outputs are
// scale-invariant); magnitude folded back every 8 steps with an rcp computed
// 2 steps earlier (drift e^{+-30} << f32 range). Output formula identical.

__device__ __forceinline__ void stage_fwd(const float* __restrict__ a_base,
                                          const float* __restrict__ b_base,
                                          int t0, int swz, int lane,
                                          float* sA, float* sB) {
#pragma unroll
  for (int s = 0; s < 16; ++s) {
    int t = t0 + s; if (t > Tdim - 1) t = Tdim - 1;
    GLOAD_LDS(&a_base[(size_t)t * (Ndim * 64) + swz], &sA[s * 64]);
  }
#pragma unroll
  for (int h = 0; h < 2; ++h) {
    int tb = t0 + h * 8 + (lane >> 3); if (tb > Tdim - 1) tb = Tdim - 1;
    GLOAD_LDS(&b_base[(size_t)tb * (Ndim * 8) + (lane & 7)], &sB[h * 64]);
  }
}

__device__ __forceinline__ void stage_bwd(const float* __restrict__ a_base,
                                          const float* __restrict__ b_base,
                                          int t0, int swz, int lane,
                                          float* sA, float* sB) {
#pragma unroll
  for (int s = 0; s < 16; ++s) {
    int t = t0 - s; if (t < 0) t = 0;
    GLOAD_LDS(&a_base[(size_t)t * (Ndim * 64) + swz], &sA[s * 64]);
  }
#pragma unroll
  for (int h = 0; h < 2; ++h) {
    int tb = t0 - 1 - (h * 8 + (lane >> 3)); if (tb < 0) tb = 0;  // b at tau-1
    GLOAD_LDS(&b_base[(size_t)tb * (Ndim * 8) + (lane & 7)], &sB[h * 64]);
  }
}

__global__ __launch_bounds__(64, 1) void chains_kernel(const float* __restrict__ A,
                                                       const float* __restrict__ Bm,
                                                       const float* __restrict__ Z1,
                                                       float* __restrict__ Fout,
                                                       float* __restrict__ Bout) {
  __shared__ float sA0[1024], sA1[1024], sB0[128], sB1[128], sLa[128];
  const int lane = threadIdx.x;
  const int x = lane >> 3, y = lane & 7;
  const int swz = (x << 3) | (y ^ x);   // involution: staging src == identity-read slot
  const int trw = (y << 3) | (x ^ y);   // transpose-read slot
  const int chain = blockIdx.x & 511;
  const int b = chain >> 6, n = chain & 63;
  const size_t cbase = ((size_t)b * Tdim) * Ndim + n;
  const float* a_base = A + cbase * 64;
  const float* b_base = Bm + cbase * 8;

  if (blockIdx.x < 512) {
    // ---- forward chain ----
    float* f_base = Fout + cbase * 8;
    float v0 = Z1[n * 8 + y] + b_base[y];
    float q = __expf(v0);                 // y(=j)-indexed, replicated across groups
    float T0 = q; SUM_LO3(T0);
    if (x == 0) f_base[y] = v0 - __logf(T0);
    q *= __builtin_amdgcn_rcpf(T0);       // one-time fold; no per-step sc
    stage_fwd(a_base, b_base, 1, swz, lane, sA0, sB0);
#pragma unroll 1
    for (int kk = 0; kk < 64; ++kk) {
      const float* sA = (kk & 1) ? sA1 : sA0;
      const float* sB = (kk & 1) ? sB1 : sB0;
      float* nA = (kk & 1) ? sA0 : sA1;
      float* nB = (kk & 1) ? sB0 : sB1;
      const int t0 = 1 + kk * 16;
      float av[16], bv[16];                            // batch burst -> regs
#pragma unroll
      for (int s = 0; s < 16; ++s) {
        av[s] = sA[s * 64 + ((s & 1) ? trw : swz)];
        bv[s] = sB[s * 8 + ((s & 1) ? y : x)];
      }
      __builtin_amdgcn_sched_barrier(0);
      if (kk + 1 < 64) stage_fwd(a_base, b_base, t0 + 16, swz, lane, nA, nB);
      __builtin_amdgcn_sched_barrier(0);
      float scF = 1.0f;
#pragma unroll
      for (int s = 0; s < 16; ++s) {                   // pure-VALU core
        int oidx = (s & 1) ? y : x;                    // output state index role
        float v = __expf(av[s]) * q;                   // CHAIN
        if (!(s & 1)) { SUM_LO3(v); } else { SUM_HI3(v); }  // CHAIN: sum over j
        float S = v * __expf(bv[s]);                   // CHAIN tail (no sc)
        if (s == 7 || s == 15) S *= scF;               // rare fold, rcp 2 steps old
        q = S;
        float T = S;                                   // norm path: OFF-chain
        if (!(s & 1)) { SUM_HI3(T); } else { SUM_LO3(T); }
        if (s == 5 || s == 13) scF = __builtin_amdgcn_rcpf(T);
        float la = __logf(S * __builtin_amdgcn_rcpf(T));  // log(S/T), off-chain
        if ((((s & 1) ? x : y)) == 0) sLa[s * 8 + oidx] = la;  // ds_write
      }
      __builtin_amdgcn_sched_barrier(0);
#pragma unroll
      for (int h = 0; h < 2; ++h) {                    // packed store: 2 dwords/lane
        int t = t0 + x + h * 8;
        if (t < Tdim) f_base[(size_t)t * (Ndim * 8) + y] = sLa[h * 64 + lane];
      }
    }
  } else {
    // ---- backward (beta) chain ----
    float* bo = Bout + cbase * 8;
    float bT = b_base[(size_t)(Tdim - 1) * (Ndim * 8) + x];
    float u = __expf(bT);                 // x(=i)-indexed (beta_{T-1}=0)
    if (x == 0) bo[(size_t)(Tdim - 1) * (Ndim * 8) + y] = 0.f;
    stage_bwd(a_base, b_base, Tdim - 1, swz, lane, sA0, sB0);
#pragma unroll 1
    for (int kk = 0; kk < 64; ++kk) {
      const float* sA = (kk & 1) ? sA1 : sA0;
      const float* sB = (kk & 1) ? sB1 : sB0;
      float* nA = (kk & 1) ? sA0 : sA1;
      float* nB = (kk & 1) ? sB0 : sB1;
      const int t0 = Tdim - 1 - kk * 16;
      float av[16], bv[16];
#pragma unroll
      for (int s = 0; s < 16; ++s) {
        av[s] = sA[s * 64 + ((s & 1) ? trw : swz)];
        bv[s] = sB[s * 8 + ((s & 1) ? x : y)];
      }
      __builtin_amdgcn_sched_barrier(0);
      if (kk + 1 < 64) stage_bwd(a_base, b_base, t0 - 16, swz, lane, nA, nB);
      __builtin_amdgcn_sched_barrier(0);
      float scB = 1.0f;
#pragma unroll
      for (int s = 0; s < 16; ++s) {
        int tau = t0 - s;
        if (tau >= 1) {
          float v = __expf(av[s]) * u;                 // CHAIN
          if (!(s & 1)) { SUM_HI3(v); } else { SUM_LO3(v); }  // CHAIN: sum over i
          int oidx = (s & 1) ? x : y;                  // r's index role
          float unew = __expf(bv[s]) * v;              // CHAIN tail (no sc)
          if (s == 7 || s == 15) unew *= scB;          // rare fold
          float W = v;                                 // norm path: OFF-chain
          if (!(s & 1)) { SUM_LO3(W); } else { SUM_HI3(W); }
          if (s == 5 || s == 13) scB = __builtin_amdgcn_rcpf(W);
          float lb = __logf(v * __builtin_amdgcn_rcpf(W));  // log(v/W), off-chain
          if ((((s & 1) ? y : x)) == 0) sLa[s * 8 + oidx] = lb;
          u = unew;
        }
      }
      __builtin_amdgcn_sched_barrier(0);
#pragma unroll
      for (int h = 0; h < 2; ++h) {
        int trow = t0 - (x + h * 8) - 1;
        if (trow >= 0) bo[(size_t)trow * (Ndim * 8) + y] = sLa[h * 64 + lane];
      }
    }
  }
}

// ---------------- kernel 2: gammas (memory-bound) ----------------
// 16 lanes per g-row: lane = (g, i, h) with h = j-half. EVERY bulk access
// (A read, F_prev read, G2 write) is one contiguous float4/lane (1KB per
// wave-instruction) — the old layout's two interleaved 16B-of-32B store
// streams are gone. j-sum = 4 in-reg exps + 1 DPP; i-sum = 3 DPPs.
__global__ __launch_bounds__(256) void gamma_kernel(const float* __restrict__ A,
                                                    const float* __restrict__ Bm,
                                                    const float* __restrict__ F,
                                                    const float* __restrict__ Bo,
                                                    float* __restrict__ G1,
                                                    float* __restrict__ G2) {
  const int tid = threadIdx.x;
  const int lane16 = tid & 15;
  const int i = (tid >> 1) & 7;                        // row index within K
  const int h = tid & 1;                               // j-half (0: j0..3, 1: j4..7)
  const int g = blockIdx.x * 16 + (tid >> 4);          // flat (b*T+t)*N+n
  const int t = (g >> 6) & (Tdim - 1);

  const float bo_i = Bo[(size_t)g * 8 + i];

  // gamma1: u1 = F+Bo, normalize over i (sum over lane bits {1,2,3})
  {
    float u1 = F[(size_t)g * 8 + i] + bo_i;
    float s1 = __expf(u1);
    s1 = DPPADD(s1, 0x4E);     // xor2  (i bit0)
    s1 = DPPADD(s1, 0x124);    // ror4  (i bit1 coset within row16)
    s1 = DPPADD(s1, 0x128);    // ror8  (i bit2 coset)
    if (h == 0) G1[(size_t)g * 8 + i] = u1 - __logf(s1);
  }

  // gamma2
  float4* o = (float4*)&G2[(size_t)g * 64 + lane16 * 4];
  if (t == 0) {
    *o = make_float4(0.f, 0.f, 0.f, 0.f);
  } else {
    float4 a4 = *(const float4*)&A[(size_t)g * 64 + lane16 * 4];
    float4 f4 = *(const float4*)&F[((size_t)g - Ndim) * 8 + h * 4];
    float c = bo_i + Bm[(size_t)g * 8 + i];
    float v0 = c + a4.x + f4.x, v1 = c + a4.y + f4.y;
    float v2 = c + a4.z + f4.z, v3 = c + a4.w + f4.w;
    float r = (__expf(v0) + __expf(v1)) + (__expf(v2) + __expf(v3));
    r = DPPADD(r, 0xB1);       // xor1: + partner j-half
    r = DPPADD(r, 0x4E);       // then sum over i (bits 1,2,3)
    r = DPPADD(r, 0x124);
    r = DPPADD(r, 0x128);
    float lq = __logf(r);
    *o = make_float4(v0 - lq, v1 - lq, v2 - lq, v3 - lq);
  }
}

extern "C" void kernel_launch(void* const* d_in, const int* in_sizes, int n_in,
                              void* d_out, int out_size, void* d_ws, size_t ws_size,
                              hipStream_t stream) {
  const float* A  = (const float*)d_in[0];   // (B,T,N,K,K)
  const float* Bm = (const float*)d_in[1];   // (B,T,N,K)
  const float* Z1 = (const float*)d_in[2];   // (N,K)
  float* out = (float*)d_out;
  float* Fout = out;                // forward_probs
  float* Bout = out + FSZ;          // backward_probs
  float* G1   = out + 2 * FSZ;      // gamma1
  float* G2   = out + 3 * FSZ;      // gamma2

  chains_kernel<<<dim3(1024), dim3(64), 0, stream>>>(A, Bm, Z1, Fout, Bout);
  gamma_kernel<<<dim3(8 * Tdim * Ndim / 16), dim3(256), 0, stream>>>(A, Bm, Fout, Bout, G1, G2);
}